// Round 5
// baseline (437.347 us; speedup 1.0000x reference)
//
#include <hip/hip_runtime.h>
#include <hip/hip_cooperative_groups.h>
#include <math.h>

namespace cg = cooperative_groups;

#define B_    32
#define CIN_  256
#define HW_   784
#define H_    28
#define W_    28
#define COUT_ 256
#define KEXP_ 4
#define HID_  64

#define SMEM_BYTES 67840   // max(phase0 4224, phase1 67840, phase2 37120, phase3 60480)

typedef short short8 __attribute__((ext_vector_type(8)));
typedef unsigned short ushort4v __attribute__((ext_vector_type(4)));
typedef float floatx16 __attribute__((ext_vector_type(16)));

__device__ __forceinline__ unsigned short f2bf(float f) {
    union { float f; unsigned int u; } v; v.f = f;
    unsigned int r = (v.u + 0x7FFFu + ((v.u >> 16) & 1u)) >> 16;
    return (unsigned short)r;
}

// ---------------- phase 0: transpose tile + partial pool ----------------
__device__ __forceinline__ void do_xpose_unit(const float* __restrict__ x,
                                              unsigned short* __restrict__ x_t,
                                              float* __restrict__ partial,
                                              char* sm, int bid, int t) {
    float (*tile)[33] = (float (*)[33])sm;
    int b   = bid / 200;
    int rem = bid - b * 200;
    int icg = rem / 25;
    int pxt = rem % 25;
    int ic0 = icg * 32;
    int px0 = pxt * 32;
    int c = t & 31, rr = t >> 5;
    #pragma unroll
    for (int r = 0; r < 4; ++r) {
        int icr = rr + r * 8;
        int px = px0 + c;
        float v = (px < HW_) ? x[((size_t)(b * CIN_ + ic0 + icr)) * HW_ + px] : 0.f;
        tile[icr][c] = v;
    }
    __syncthreads();
    #pragma unroll
    for (int r = 0; r < 4; ++r) {
        int pxr = rr + r * 8;
        int px = px0 + pxr;
        if (px < HW_)
            x_t[((size_t)b * HW_ + px) * CIN_ + ic0 + c] = f2bf(tile[c][pxr]);
    }
    if (t < 32) {
        float s = 0.f;
        #pragma unroll
        for (int cc = 0; cc < 32; ++cc) s += tile[t][cc];
        partial[((size_t)b * 25 + pxt) * CIN_ + ic0 + t] = s * (1.0f / HW_);
    }
    __syncthreads();   // tile reused by next unit
}

// ---------------- phase 1: SE MLP + softmax over K ----------------
__device__ __forceinline__ void do_se(const float* __restrict__ partial,
                                      const float* __restrict__ fc1_w,
                                      const float* __restrict__ fc2_w,
                                      const float* __restrict__ fc2_b,
                                      float* __restrict__ prob,
                                      char* sm, int b, int t) {
    float* pl = (float*)sm;       // 256
    float* h  = pl + 256;         // 64
    float* wb = h + 64;           // 16640
    {
        float s = 0.f;
        for (int pt = 0; pt < 25; ++pt)
            s += partial[((size_t)b * 25 + pt) * CIN_ + t];
        pl[t] = s;
    }
    #pragma unroll
    for (int i = 0; i < 16; ++i) {
        int l = t + i * 256;
        float4 v = *(const float4*)(fc1_w + (size_t)l * 4);
        int r = l >> 6, cc = (l & 63) * 4;
        float* dst = &wb[r * 257 + cc];
        dst[0] = v.x; dst[1] = v.y; dst[2] = v.z; dst[3] = v.w;
    }
    __syncthreads();
    if (t < HID_) {
        float s = 0.f;
        const float* wr = &wb[t * 257];
        for (int c = 0; c < CIN_; ++c) s += pl[c] * wr[c];
        h[t] = fmaxf(s, 0.f);
    }
    float yk[KEXP_];
    for (int k = 0; k < KEXP_; ++k) {
        __syncthreads();
        #pragma unroll
        for (int i = 0; i < 16; ++i) {
            int l = t + i * 256;
            float4 v = *(const float4*)(fc2_w + (size_t)k * COUT_ * HID_ + (size_t)l * 4);
            int o = l >> 4, jj = (l & 15) * 4;
            float* dst = &wb[o * 65 + jj];
            dst[0] = v.x; dst[1] = v.y; dst[2] = v.z; dst[3] = v.w;
        }
        __syncthreads();
        float s = fc2_b[k * COUT_ + t];
        const float* wr = &wb[t * 65];
        #pragma unroll
        for (int j = 0; j < HID_; ++j) s += h[j] * wr[j];
        yk[k] = s * 0.125f;
    }
    float m = yk[0];
    for (int k = 1; k < KEXP_; ++k) m = fmaxf(m, yk[k]);
    float e[KEXP_], sum = 0.f;
    for (int k = 0; k < KEXP_; ++k) { e[k] = expf(yk[k] - m); sum += e[k]; }
    float inv = 1.0f / sum;
    for (int k = 0; k < KEXP_; ++k)
        prob[b * (KEXP_ * COUT_) + k * COUT_ + t] = e[k] * inv;
}

// ---------------- phase 2: aggregate expert weights for one oc, 16 b's ----------------
__device__ __forceinline__ void do_agg_unit(const float* __restrict__ weight,
                                            const float* __restrict__ prob,
                                            unsigned short* __restrict__ agg,
                                            char* sm, int oc, int b0, int t) {
    float* ws_w = (float*)sm;      // 9216 floats
    float* pb   = ws_w + 9216;     // [4][16]
    #pragma unroll
    for (int i = 0; i < 9; ++i) {
        int e4 = t + i * 256;
        int k = e4 / 576;
        int r4 = e4 - k * 576;
        float4 v = *(const float4*)(weight + (size_t)k * 589824 + (size_t)oc * 2304 + (size_t)r4 * 4);
        *(float4*)&ws_w[e4 * 4] = v;
    }
    if (t < 64) {
        int k = t >> 4, bb = t & 15;
        pb[k * 16 + bb] = prob[(size_t)(b0 + bb) * (KEXP_ * COUT_) + k * COUT_ + oc];
    }
    __syncthreads();
    int icg = t & 63, blane = t >> 6;
    for (int rs = 0; rs < 9; ++rs) {
        float wv[4][4];
        #pragma unroll
        for (int q = 0; q < 4; ++q)
            #pragma unroll
            for (int k = 0; k < 4; ++k)
                wv[q][k] = ws_w[k * 2304 + (icg * 4 + q) * 9 + rs];
        #pragma unroll
        for (int bb = 0; bb < 4; ++bb) {
            int bidx = blane * 4 + bb;
            float p0 = pb[0 * 16 + bidx], p1 = pb[1 * 16 + bidx];
            float p2 = pb[2 * 16 + bidx], p3 = pb[3 * 16 + bidx];
            ushort4v pack;
            #pragma unroll
            for (int q = 0; q < 4; ++q) {
                float s = p0 * wv[q][0] + p1 * wv[q][1] + p2 * wv[q][2] + p3 * wv[q][3];
                pack[q] = f2bf(s);
            }
            *(ushort4v*)(agg + (((size_t)(b0 + bidx) * 9 + rs) * COUT_ + oc) * CIN_ + icg * 4) = pack;
        }
    }
    __syncthreads();
}

// ---------------- phase 3: MFMA implicit-GEMM conv (4 output rows / block) ----------------
// gid in [0,448): b = gid&31, oc0 = ((gid>>5)&1)*128, rowblk = gid>>6 (7 rowblks of 4 rows)
__device__ void do_conv(const unsigned short* __restrict__ x_t,
                        const unsigned short* __restrict__ agg,
                        float* __restrict__ out,
                        char* sm, int gid, int t) {
    short* Xs0 = (short*)sm;           // 6*35*72 = 15120 shorts
    short* Xs1 = Xs0 + 15120;

    int b      = gid & 31;
    int oc0    = ((gid >> 5) & 1) * 128;
    int rowblk = gid >> 6;
    int py0 = rowblk * 4;

    int lane = t & 63, w = t >> 6;
    int ml = lane & 31, kh = lane >> 5;

    floatx16 acc[4];
    #pragma unroll
    for (int j = 0; j < 4; ++j)
        #pragma unroll
        for (int r = 0; r < 16; ++r) acc[j][r] = 0.f;

    const unsigned short* xtb = x_t + (size_t)b * HW_ * CIN_;
    const unsigned short* aln = agg + (((size_t)b * 9 * COUT_) + oc0 + w * 32 + ml) * CIN_ + kh * 8;

    // stage chunk 0 (ic 0..63) into Xs0: rows py0-1..py0+4, cols -1..33
    #pragma unroll
    for (int i = 0; i < 7; ++i) {
        int l = t + i * 256;
        if (l < 1680) {
            int pos = l >> 3, g = l & 7;
            int row = pos / 35, col = pos - row * 35;
            int gy = py0 - 1 + row, gx = col - 1;
            short8 v = (short8)0;
            if ((unsigned)gy < 28u && (unsigned)gx < 28u)
                v = *(const short8*)(xtb + ((size_t)(gy * W_ + gx)) * CIN_ + g * 8);
            *(short8*)&Xs0[pos * 72 + g * 8] = v;
        }
    }

    // prologue A: taps (dy=0,1,2, dx=0) at ic-chunk 0, kk 0
    short8 Acur0, Acur1, Acur2, Anext0, Anext1, Anext2;
    Acur0 = *(const short8*)(aln + (size_t)0 * (COUT_ * CIN_));
    Acur1 = *(const short8*)(aln + (size_t)3 * (COUT_ * CIN_));
    Acur2 = *(const short8*)(aln + (size_t)6 * (COUT_ * CIN_));
    int dxn = 1, kkn = 0, icn = 0;

    __syncthreads();

    for (int c = 0; c < 4; ++c) {
        int ic0 = c * 64;
        const short* xb = (c & 1) ? Xs1 : Xs0;
        short*       xo = (c & 1) ? Xs0 : Xs1;

        short8 Xl[7];
        if (c < 3) {
            #pragma unroll
            for (int i = 0; i < 7; ++i) {
                int l = t + i * 256;
                short8 v = (short8)0;
                if (l < 1680) {
                    int pos = l >> 3, g = l & 7;
                    int row = pos / 35, col = pos - row * 35;
                    int gy = py0 - 1 + row, gx = col - 1;
                    if ((unsigned)gy < 28u && (unsigned)gx < 28u)
                        v = *(const short8*)(xtb + ((size_t)(gy * W_ + gx)) * CIN_ + ic0 + 64 + g * 8);
                }
                Xl[i] = v;
            }
        }

        for (int kk = 0; kk < 4; ++kk) {
            for (int dx = 0; dx < 3; ++dx) {
                if (icn < 256) {
                    const unsigned short* ap = aln + icn + kkn * 16;
                    Anext0 = *(const short8*)(ap + (size_t)(0 * 3 + dxn) * (COUT_ * CIN_));
                    Anext1 = *(const short8*)(ap + (size_t)(1 * 3 + dxn) * (COUT_ * CIN_));
                    Anext2 = *(const short8*)(ap + (size_t)(2 * 3 + dxn) * (COUT_ * CIN_));
                    ++dxn;
                    if (dxn == 3) { dxn = 0; ++kkn; if (kkn == 4) { kkn = 0; icn += 64; } }
                }
                int va = (ml + dx) * 72 + kk * 16 + kh * 8;
                #pragma unroll
                for (int r = 0; r < 6; ++r) {
                    short8 Bf = *(const short8*)&xb[r * 2520 + va];
                    if (r <= 3)
                        acc[r]     = __builtin_amdgcn_mfma_f32_32x32x16_bf16(Acur0, Bf, acc[r], 0, 0, 0);
                    if (r >= 1 && r <= 4)
                        acc[r - 1] = __builtin_amdgcn_mfma_f32_32x32x16_bf16(Acur1, Bf, acc[r - 1], 0, 0, 0);
                    if (r >= 2)
                        acc[r - 2] = __builtin_amdgcn_mfma_f32_32x32x16_bf16(Acur2, Bf, acc[r - 2], 0, 0, 0);
                }
                Acur0 = Anext0; Acur1 = Anext1; Acur2 = Anext2;
            }
        }

        if (c < 3) {
            #pragma unroll
            for (int i = 0; i < 7; ++i) {
                int l = t + i * 256;
                if (l < 1680) {
                    int pos = l >> 3, g = l & 7;
                    *(short8*)&xo[pos * 72 + g * 8] = Xl[i];
                }
            }
        }
        __syncthreads();
    }

    // epilogue: D layout col=lane&31, row=(reg&3)+8*(reg>>2)+4*(lane>>5)
    if (ml < W_) {
        #pragma unroll
        for (int j = 0; j < 4; ++j) {
            float* op = out + ((size_t)(b * COUT_ + oc0 + w * 32)) * HW_ + (py0 + j) * W_ + ml;
            #pragma unroll
            for (int r = 0; r < 16; ++r) {
                int ocd = (r & 3) + 8 * (r >> 2) + 4 * kh;
                op[(size_t)ocd * HW_] = acc[j][r];
            }
        }
    }
}

// ---------------- fused cooperative kernel ----------------
__global__ void __launch_bounds__(256, 2) fused_kernel(const float* __restrict__ x,
                                                       const float* __restrict__ fc1_w,
                                                       const float* __restrict__ fc2_w,
                                                       const float* __restrict__ fc2_b,
                                                       const float* __restrict__ weight,
                                                       unsigned short* __restrict__ x_t,
                                                       unsigned short* __restrict__ agg,
                                                       float* __restrict__ partial,
                                                       float* __restrict__ prob,
                                                       float* __restrict__ out) {
    __shared__ __align__(16) char sm[SMEM_BYTES];
    cg::grid_group grid = cg::this_grid();
    int g = blockIdx.x, t = threadIdx.x;

    // phase 0: 6400 tiles over 512 blocks
    for (int i = 0; i < 13; ++i) {
        int bid = g + 512 * i;
        if (bid < 6400) do_xpose_unit(x, x_t, partial, sm, bid, t);
    }
    __threadfence();
    grid.sync();

    // phase 1: SE for 32 samples
    if (g < 32) do_se(partial, fc1_w, fc2_w, fc2_b, prob, sm, g, t);
    __threadfence();
    grid.sync();

    // phase 2: aggregation, one oc x 16-b group per block
    do_agg_unit(weight, prob, agg, sm, g & 255, (g >> 8) * 16, t);
    __threadfence();
    grid.sync();

    // phase 3: conv
    if (g < 448) do_conv(x_t, agg, out, sm, g, t);
}

// ---------------- standalone fallback chain (if coop launch rejected) ----------------
__global__ __launch_bounds__(256) void k_xpose(const float* __restrict__ x,
                                               unsigned short* __restrict__ x_t,
                                               float* __restrict__ partial) {
    __shared__ __align__(16) char sm[4224];
    do_xpose_unit(x, x_t, partial, sm, blockIdx.x, threadIdx.x);
}
__global__ __launch_bounds__(256) void k_se(const float* __restrict__ partial,
                                            const float* __restrict__ fc1_w,
                                            const float* __restrict__ fc2_w,
                                            const float* __restrict__ fc2_b,
                                            float* __restrict__ prob) {
    __shared__ __align__(16) char sm[67840];
    do_se(partial, fc1_w, fc2_w, fc2_b, prob, sm, blockIdx.x, threadIdx.x);
}
__global__ __launch_bounds__(256) void k_agg(const float* __restrict__ weight,
                                             const float* __restrict__ prob,
                                             unsigned short* __restrict__ agg) {
    __shared__ __align__(16) char sm[37120];
    do_agg_unit(weight, prob, agg, sm, blockIdx.x & 255, (blockIdx.x >> 8) * 16, threadIdx.x);
}
__global__ __launch_bounds__(256, 2) void k_conv(const unsigned short* __restrict__ x_t,
                                                 const unsigned short* __restrict__ agg,
                                                 float* __restrict__ out) {
    __shared__ __align__(16) char sm[60480];
    do_conv(x_t, agg, out, sm, blockIdx.x, threadIdx.x);
}

extern "C" void kernel_launch(void* const* d_in, const int* in_sizes, int n_in,
                              void* d_out, int out_size, void* d_ws, size_t ws_size,
                              hipStream_t stream) {
    const float* x     = (const float*)d_in[0];
    const float* fc1_w = (const float*)d_in[1];
    const float* fc2_w = (const float*)d_in[2];
    const float* fc2_b = (const float*)d_in[3];
    const float* weight= (const float*)d_in[4];
    float* out = (float*)d_out;

    char* ws = (char*)d_ws;
    float* prob = (float*)(ws);                                   // 131072 B
    unsigned short* x_t = (unsigned short*)(ws + 131072);         // 12,845,056 B
    unsigned short* agg = (unsigned short*)(ws + 12976128);       // 37,748,736 B
    float* partial = (float*)(ws + 12976128);                     // 819,200 B (overlaps agg; consumed first)

    void* args[] = {(void*)&x, (void*)&fc1_w, (void*)&fc2_w, (void*)&fc2_b, (void*)&weight,
                    (void*)&x_t, (void*)&agg, (void*)&partial, (void*)&prob, (void*)&out};
    hipError_t err = hipLaunchCooperativeKernel((const void*)fused_kernel,
                                                dim3(512), dim3(256), args, 0, stream);
    if (err != hipSuccess) {
        k_xpose<<<6400, 256, 0, stream>>>(x, x_t, partial);
        k_se<<<32, 256, 0, stream>>>(partial, fc1_w, fc2_w, fc2_b, prob);
        k_agg<<<512, 256, 0, stream>>>(weight, prob, agg);
        k_conv<<<448, 256, 0, stream>>>(x_t, agg, out);
    }
}

// Round 6
// 158.717 us; speedup vs baseline: 2.7555x; 2.7555x over previous
//
#include <hip/hip_runtime.h>
#include <math.h>

#define B_    32
#define CIN_  256
#define HW_   784
#define H_    28
#define W_    28
#define COUT_ 256
#define KEXP_ 4
#define HID_  64

typedef short short8 __attribute__((ext_vector_type(8)));
typedef unsigned short ushort4v __attribute__((ext_vector_type(4)));
typedef float floatx16 __attribute__((ext_vector_type(16)));

__device__ __forceinline__ unsigned short f2bf(float f) {
    union { float f; unsigned int u; } v; v.f = f;
    unsigned int r = (v.u + 0x7FFFu + ((v.u >> 16) & 1u)) >> 16;
    return (unsigned short)r;
}

// ---------------- Kernel 1: transpose + partial pool ----------------
__global__ __launch_bounds__(256) void xpose_pool_kernel(const float* __restrict__ x,
                                                         unsigned short* __restrict__ x_t,
                                                         float* __restrict__ partial) {
    __shared__ float tile[32][33];
    int bid = blockIdx.x;              // 32 * 8 * 25
    int b   = bid / 200;
    int rem = bid - b * 200;
    int icg = rem / 25;
    int pxt = rem % 25;
    int ic0 = icg * 32;
    int px0 = pxt * 32;
    int t = threadIdx.x;
    int c = t & 31, rr = t >> 5;
    #pragma unroll
    for (int r = 0; r < 4; ++r) {
        int icr = rr + r * 8;
        int px = px0 + c;
        float v = (px < HW_) ? x[((size_t)(b * CIN_ + ic0 + icr)) * HW_ + px] : 0.f;
        tile[icr][c] = v;
    }
    __syncthreads();
    #pragma unroll
    for (int r = 0; r < 4; ++r) {
        int pxr = rr + r * 8;
        int px = px0 + pxr;
        if (px < HW_)
            x_t[((size_t)b * HW_ + px) * CIN_ + ic0 + c] = f2bf(tile[c][pxr]);
    }
    if (t < 32) {
        float s = 0.f;
        #pragma unroll
        for (int cc = 0; cc < 32; ++cc) s += tile[t][cc];
        partial[((size_t)b * 25 + pxt) * CIN_ + ic0 + t] = s * (1.0f / HW_);
    }
}

// ---------------- standalone pool (fallback path only) ----------------
__global__ __launch_bounds__(256) void pool_kernel(const float* __restrict__ x,
                                                   float* __restrict__ pooled) {
    int w = blockIdx.x * 4 + (threadIdx.x >> 6);
    int lane = threadIdx.x & 63;
    const float* p = x + (size_t)w * HW_;
    float s = 0.f;
    for (int i = lane; i < HW_; i += 64) s += p[i];
    for (int off = 32; off; off >>= 1) s += __shfl_down(s, off);
    if (lane == 0) pooled[w] = s * (1.0f / HW_);
}

// ---------------- Kernel 2: SE MLP + softmax (reads partial pools) ----------------
__global__ __launch_bounds__(256) void se3_kernel(const float* __restrict__ partial,
                                                  const float* __restrict__ fc1_w,
                                                  const float* __restrict__ fc2_w,
                                                  const float* __restrict__ fc2_b,
                                                  float* __restrict__ prob) {
    __shared__ float pl[CIN_];
    __shared__ float h[HID_];
    __shared__ float wb[16640];
    int b = blockIdx.x, t = threadIdx.x;
    {
        float s = 0.f;
        for (int pt = 0; pt < 25; ++pt)
            s += partial[((size_t)b * 25 + pt) * CIN_ + t];
        pl[t] = s;
    }
    #pragma unroll
    for (int i = 0; i < 16; ++i) {
        int l = t + i * 256;
        float4 v = *(const float4*)(fc1_w + (size_t)l * 4);
        int r = l >> 6, cc = (l & 63) * 4;
        float* dst = &wb[r * 257 + cc];
        dst[0] = v.x; dst[1] = v.y; dst[2] = v.z; dst[3] = v.w;
    }
    __syncthreads();
    if (t < HID_) {
        float s = 0.f;
        const float* wr = &wb[t * 257];
        for (int c = 0; c < CIN_; ++c) s += pl[c] * wr[c];
        h[t] = fmaxf(s, 0.f);
    }
    float yk[KEXP_];
    for (int k = 0; k < KEXP_; ++k) {
        __syncthreads();
        #pragma unroll
        for (int i = 0; i < 16; ++i) {
            int l = t + i * 256;
            float4 v = *(const float4*)(fc2_w + (size_t)k * COUT_ * HID_ + (size_t)l * 4);
            int o = l >> 4, jj = (l & 15) * 4;
            float* dst = &wb[o * 65 + jj];
            dst[0] = v.x; dst[1] = v.y; dst[2] = v.z; dst[3] = v.w;
        }
        __syncthreads();
        float s = fc2_b[k * COUT_ + t];
        const float* wr = &wb[t * 65];
        #pragma unroll
        for (int j = 0; j < HID_; ++j) s += h[j] * wr[j];
        yk[k] = s * 0.125f;
    }
    float m = yk[0];
    for (int k = 1; k < KEXP_; ++k) m = fmaxf(m, yk[k]);
    float e[KEXP_], sum = 0.f;
    for (int k = 0; k < KEXP_; ++k) { e[k] = expf(yk[k] - m); sum += e[k]; }
    float inv = 1.0f / sum;
    for (int k = 0; k < KEXP_; ++k)
        prob[b * (KEXP_ * COUT_) + k * COUT_ + t] = e[k] * inv;
}

// ---------------- SE from pooled (fallback path only) ----------------
__global__ __launch_bounds__(256) void se2_kernel(const float* __restrict__ pooled,
                                                  const float* __restrict__ fc1_w,
                                                  const float* __restrict__ fc2_w,
                                                  const float* __restrict__ fc2_b,
                                                  float* __restrict__ prob) {
    __shared__ float pl[CIN_];
    __shared__ float h[HID_];
    __shared__ float wb[16640];
    int b = blockIdx.x, t = threadIdx.x;
    pl[t] = pooled[b * CIN_ + t];
    #pragma unroll
    for (int i = 0; i < 16; ++i) {
        int l = t + i * 256;
        float4 v = *(const float4*)(fc1_w + (size_t)l * 4);
        int r = l >> 6, cc = (l & 63) * 4;
        float* dst = &wb[r * 257 + cc];
        dst[0] = v.x; dst[1] = v.y; dst[2] = v.z; dst[3] = v.w;
    }
    __syncthreads();
    if (t < HID_) {
        float s = 0.f;
        const float* wr = &wb[t * 257];
        for (int c = 0; c < CIN_; ++c) s += pl[c] * wr[c];
        h[t] = fmaxf(s, 0.f);
    }
    float yk[KEXP_];
    for (int k = 0; k < KEXP_; ++k) {
        __syncthreads();
        #pragma unroll
        for (int i = 0; i < 16; ++i) {
            int l = t + i * 256;
            float4 v = *(const float4*)(fc2_w + (size_t)k * COUT_ * HID_ + (size_t)l * 4);
            int o = l >> 4, jj = (l & 15) * 4;
            float* dst = &wb[o * 65 + jj];
            dst[0] = v.x; dst[1] = v.y; dst[2] = v.z; dst[3] = v.w;
        }
        __syncthreads();
        float s = fc2_b[k * COUT_ + t];
        const float* wr = &wb[t * 65];
        #pragma unroll
        for (int j = 0; j < HID_; ++j) s += h[j] * wr[j];
        yk[k] = s * 0.125f;
    }
    float m = yk[0];
    for (int k = 1; k < KEXP_; ++k) m = fmaxf(m, yk[k]);
    float e[KEXP_], sum = 0.f;
    for (int k = 0; k < KEXP_; ++k) { e[k] = expf(yk[k] - m); sum += e[k]; }
    float inv = 1.0f / sum;
    for (int k = 0; k < KEXP_; ++k)
        prob[b * (KEXP_ * COUT_) + k * COUT_ + t] = e[k] * inv;
}

// ---------------- Kernel 3: aggregate -> agg[b][rs][oc][ic] bf16 (bgroup 16) ----------------
// grid = 512: oc = bid&255, b0 = (bid>>8)*16
__global__ __launch_bounds__(256) void agg4_kernel(const float* __restrict__ weight,
                                                   const float* __restrict__ prob,
                                                   unsigned short* __restrict__ agg) {
    __shared__ float ws_w[KEXP_ * CIN_ * 9];   // 36.9 KB
    __shared__ float pb[KEXP_][16];
    int bid = blockIdx.x;
    int oc = bid & 255;
    int b0 = (bid >> 8) * 16;
    int t = threadIdx.x;
    #pragma unroll
    for (int i = 0; i < 9; ++i) {
        int e4 = t + i * 256;                  // < 2304 float4s
        int k = e4 / 576;
        int r4 = e4 - k * 576;
        float4 v = *(const float4*)(weight + (size_t)k * 589824 + (size_t)oc * 2304 + (size_t)r4 * 4);
        *(float4*)&ws_w[e4 * 4] = v;
    }
    if (t < 64) {
        int k = t >> 4, bb = t & 15;
        pb[k][bb] = prob[(size_t)(b0 + bb) * (KEXP_ * COUT_) + k * COUT_ + oc];
    }
    __syncthreads();
    int icg = t & 63, blane = t >> 6;
    for (int rs = 0; rs < 9; ++rs) {
        float wv[4][4];
        #pragma unroll
        for (int q = 0; q < 4; ++q)
            #pragma unroll
            for (int k = 0; k < 4; ++k)
                wv[q][k] = ws_w[k * 2304 + (icg * 4 + q) * 9 + rs];
        #pragma unroll
        for (int bb = 0; bb < 4; ++bb) {
            int bidx = blane * 4 + bb;
            float p0 = pb[0][bidx], p1 = pb[1][bidx], p2 = pb[2][bidx], p3 = pb[3][bidx];
            ushort4v pack;
            #pragma unroll
            for (int q = 0; q < 4; ++q) {
                float s = p0 * wv[q][0] + p1 * wv[q][1] + p2 * wv[q][2] + p3 * wv[q][3];
                pack[q] = f2bf(s);
            }
            *(ushort4v*)(agg + (((size_t)(b0 + bidx) * 9 + rs) * COUT_ + oc) * CIN_ + icg * 4) = pack;
        }
    }
}

// ---------------- Kernel 4: MFMA conv, single-buffer Xs, 3-4 blocks/CU ----------------
// grid = 448: b = gid&31, oc0 = ((gid>>5)&1)*128, rowblk = gid>>6 (0..6), 4 rows each
__global__ __launch_bounds__(256, 3) void conv_mfma4_kernel(const unsigned short* __restrict__ x_t,
                                                            const unsigned short* __restrict__ agg,
                                                            float* __restrict__ out) {
    __shared__ __align__(16) short Xs[6 * 35 * 72];   // 30240 B

    int gid = blockIdx.x;
    int b      = gid & 31;
    int oc0    = ((gid >> 5) & 1) * 128;
    int rowblk = gid >> 6;
    int py0 = rowblk * 4;

    int t = threadIdx.x;
    int lane = t & 63, w = t >> 6;
    int ml = lane & 31, kh = lane >> 5;

    floatx16 acc[4];
    #pragma unroll
    for (int j = 0; j < 4; ++j)
        #pragma unroll
        for (int r = 0; r < 16; ++r) acc[j][r] = 0.f;

    const unsigned short* xtb = x_t + (size_t)b * HW_ * CIN_;
    const unsigned short* aln = agg + (((size_t)b * 9 * COUT_) + oc0 + w * 32 + ml) * CIN_ + kh * 8;

    // prologue A: taps rs = 0,3,6 (dy=0,1,2 at dx=0), ic-chunk 0, kk 0
    short8 Acur0, Acur1, Acur2, Anext0, Anext1, Anext2;
    Acur0 = *(const short8*)(aln + (size_t)0 * (COUT_ * CIN_));
    Acur1 = *(const short8*)(aln + (size_t)3 * (COUT_ * CIN_));
    Acur2 = *(const short8*)(aln + (size_t)6 * (COUT_ * CIN_));
    int dxn = 1, kkn = 0, icn = 0;

    for (int c = 0; c < 4; ++c) {
        if (c) __syncthreads();   // all reads of previous chunk done
        // stage Xs: rows py0-1..py0+4, cols -1..33, ic chunk c
        #pragma unroll
        for (int i = 0; i < 7; ++i) {
            int l = t + i * 256;
            if (l < 1680) {
                int pos = l >> 3, g = l & 7;
                int row = pos / 35, col = pos - row * 35;
                int gy = py0 - 1 + row, gx = col - 1;
                short8 v = (short8)0;
                if ((unsigned)gy < 28u && (unsigned)gx < 28u)
                    v = *(const short8*)(xtb + ((size_t)(gy * W_ + gx)) * CIN_ + c * 64 + g * 8);
                *(short8*)&Xs[pos * 72 + g * 8] = v;
            }
        }
        __syncthreads();

        for (int kk = 0; kk < 4; ++kk) {
            for (int dx = 0; dx < 3; ++dx) {
                // rolling A prefetch for the next (chunk,kk,dx)
                if (icn < 256) {
                    const unsigned short* ap = aln + icn + kkn * 16;
                    Anext0 = *(const short8*)(ap + (size_t)(0 * 3 + dxn) * (COUT_ * CIN_));
                    Anext1 = *(const short8*)(ap + (size_t)(1 * 3 + dxn) * (COUT_ * CIN_));
                    Anext2 = *(const short8*)(ap + (size_t)(2 * 3 + dxn) * (COUT_ * CIN_));
                    ++dxn;
                    if (dxn == 3) { dxn = 0; ++kkn; if (kkn == 4) { kkn = 0; icn += 64; } }
                }
                int va = (ml + dx) * 72 + kk * 16 + kh * 8;
                #pragma unroll
                for (int r = 0; r < 6; ++r) {
                    short8 Bf = *(const short8*)&Xs[r * 2520 + va];
                    if (r <= 3)
                        acc[r]     = __builtin_amdgcn_mfma_f32_32x32x16_bf16(Acur0, Bf, acc[r], 0, 0, 0);
                    if (r >= 1 && r <= 4)
                        acc[r - 1] = __builtin_amdgcn_mfma_f32_32x32x16_bf16(Acur1, Bf, acc[r - 1], 0, 0, 0);
                    if (r >= 2)
                        acc[r - 2] = __builtin_amdgcn_mfma_f32_32x32x16_bf16(Acur2, Bf, acc[r - 2], 0, 0, 0);
                }
                Acur0 = Anext0; Acur1 = Anext1; Acur2 = Anext2;
            }
        }
    }

    // epilogue: D layout col=lane&31, row=(reg&3)+8*(reg>>2)+4*(lane>>5)
    if (ml < W_) {
        #pragma unroll
        for (int j = 0; j < 4; ++j) {
            float* op = out + ((size_t)(b * COUT_ + oc0 + w * 32)) * HW_ + (py0 + j) * W_ + ml;
            #pragma unroll
            for (int r = 0; r < 16; ++r) {
                int ocd = (r & 3) + 8 * (r >> 2) + 4 * kh;
                op[(size_t)ocd * HW_] = acc[j][r];
            }
        }
    }
}

// ---------------- Fallback fp32 direct conv ----------------
__global__ __launch_bounds__(256) void conv_kernel(const float* __restrict__ x,
                                                   const float* __restrict__ weight,
                                                   const float* __restrict__ prob,
                                                   float* __restrict__ out) {
    __shared__ float xs[30 * 30];
    __shared__ float wagg[8][32][12];
    __shared__ float pl[KEXP_][8];

    int b  = blockIdx.x >> 5;
    int o0 = (blockIdx.x & 31) * 8;
    int t  = threadIdx.x;

    if (t < 32) {
        int k = t >> 3, oc = t & 7;
        pl[k][oc] = prob[b * (KEXP_ * COUT_) + k * COUT_ + o0 + oc];
    }
    int p0 = t;
    int pr[4], pc[4];
    bool pv[4];
    #pragma unroll
    for (int j = 0; j < 4; ++j) {
        int p = p0 + j * 256;
        pv[j] = p < HW_;
        pr[j] = p / W_;
        pc[j] = p % W_;
    }
    float acc[8][4];
    #pragma unroll
    for (int oc = 0; oc < 8; ++oc)
        #pragma unroll
        for (int j = 0; j < 4; ++j) acc[oc][j] = 0.f;

    int aoc = t >> 5, aii = t & 31;

    for (int ic0 = 0; ic0 < CIN_; ic0 += 32) {
        __syncthreads();
        {
            float w9[9];
            #pragma unroll
            for (int j = 0; j < 9; ++j) w9[j] = 0.f;
            int i = ic0 + aii;
            #pragma unroll
            for (int k = 0; k < KEXP_; ++k) {
                float pk = pl[k][aoc];
                const float* wp = weight + ((size_t)(k * COUT_ + o0 + aoc) * CIN_ + i) * 9;
                #pragma unroll
                for (int j = 0; j < 9; ++j) w9[j] += pk * wp[j];
            }
            #pragma unroll
            for (int j = 0; j < 9; ++j) wagg[aoc][aii][j] = w9[j];
        }
        for (int ii = 0; ii < 32; ++ii) {
            int i = ic0 + ii;
            __syncthreads();
            const float* xp = x + (size_t)(b * CIN_ + i) * HW_;
            for (int e = t; e < 900; e += 256) {
                int ry = e / 30, cx = e - ry * 30;
                int gy = ry - 1, gx = cx - 1;
                float v = 0.f;
                if ((unsigned)gy < 28u && (unsigned)gx < 28u) v = xp[gy * W_ + gx];
                xs[e] = v;
            }
            __syncthreads();
            float xv[4][9];
            #pragma unroll
            for (int j = 0; j < 4; ++j) {
                if (pv[j]) {
                    const float* xr = &xs[pr[j] * 30 + pc[j]];
                    xv[j][0] = xr[0];  xv[j][1] = xr[1];  xv[j][2] = xr[2];
                    xv[j][3] = xr[30]; xv[j][4] = xr[31]; xv[j][5] = xr[32];
                    xv[j][6] = xr[60]; xv[j][7] = xr[61]; xv[j][8] = xr[62];
                } else {
                    #pragma unroll
                    for (int q = 0; q < 9; ++q) xv[j][q] = 0.f;
                }
            }
            #pragma unroll
            for (int oc = 0; oc < 8; ++oc) {
                float4 wa = *(const float4*)&wagg[oc][ii][0];
                float4 wb2 = *(const float4*)&wagg[oc][ii][4];
                float  wc = wagg[oc][ii][8];
                #pragma unroll
                for (int j = 0; j < 4; ++j) {
                    acc[oc][j] += xv[j][0] * wa.x + xv[j][1] * wa.y + xv[j][2] * wa.z
                                + xv[j][3] * wa.w + xv[j][4] * wb2.x + xv[j][5] * wb2.y
                                + xv[j][6] * wb2.z + xv[j][7] * wb2.w + xv[j][8] * wc;
                }
            }
        }
    }
    #pragma unroll
    for (int oc = 0; oc < 8; ++oc) {
        float* op = out + (size_t)(b * COUT_ + o0 + oc) * HW_ + p0;
        #pragma unroll
        for (int j = 0; j < 4; ++j)
            if (pv[j]) op[j * 256] = acc[oc][j];
    }
}

extern "C" void kernel_launch(void* const* d_in, const int* in_sizes, int n_in,
                              void* d_out, int out_size, void* d_ws, size_t ws_size,
                              hipStream_t stream) {
    const float* x     = (const float*)d_in[0];
    const float* fc1_w = (const float*)d_in[1];
    const float* fc2_w = (const float*)d_in[2];
    const float* fc2_b = (const float*)d_in[3];
    const float* weight= (const float*)d_in[4];
    float* out = (float*)d_out;

    char* ws = (char*)d_ws;
    float* prob = (float*)(ws);                                   // 131072 B
    unsigned short* x_t = (unsigned short*)(ws + 131072);         // 12,845,056 B
    unsigned short* agg = (unsigned short*)(ws + 12976128);       // 37,748,736 B
    float* partial = (float*)(ws + 12976128);                     // 819,200 B (overlaps agg; consumed before agg writes)
    const size_t WS_NEED = 12976128 + (size_t)B_ * 9 * COUT_ * CIN_ * 2;  // 50,724,864

    if (ws_size >= WS_NEED) {
        xpose_pool_kernel<<<B_ * 8 * 25, 256, 0, stream>>>(x, x_t, partial);
        se3_kernel<<<B_, 256, 0, stream>>>(partial, fc1_w, fc2_w, fc2_b, prob);
        agg4_kernel<<<512, 256, 0, stream>>>(weight, prob, agg);
        conv_mfma4_kernel<<<448, 256, 0, stream>>>(x_t, agg, out);
    } else {
        float* pooled = (float*)(ws + 131072);
        pool_kernel<<<(B_ * CIN_) / 4, 256, 0, stream>>>(x, pooled);
        se2_kernel<<<B_, 256, 0, stream>>>(pooled, fc1_w, fc2_w, fc2_b, prob);
        conv_kernel<<<B_ * (COUT_ / 8), 256, 0, stream>>>(x, weight, prob, out);
    }
}